// Round 7
// baseline (3285.999 us; speedup 1.0000x reference)
//
#include <hip/hip_runtime.h>
#include <stdint.h>

typedef unsigned short u16;
typedef unsigned char u8;
typedef unsigned long long u64;
typedef short s16x8 __attribute__((ext_vector_type(8)));
typedef float f32x4 __attribute__((ext_vector_type(4)));
typedef float f32x2 __attribute__((ext_vector_type(2)));
typedef unsigned int u32x4 __attribute__((ext_vector_type(4)));
typedef unsigned int u32x2 __attribute__((ext_vector_type(2)));

#define NB 128
#define NT 512
#define NH 256
#define GQ 8      // batch groups
#define MBQ 16    // batch rows per group
#define STEPS 511

// ---- workspace layout (bytes) ----
#define WS_HBUF 0        // double-buffered h: 2 * GQ * MBQ * 256 * 2B = 131072
#define WS_X12  131072   // 12*64 floats = 3072
#define WS_BAR  134144   // 8 groups * 4 flags * 128B = 4096

// ---- dynamic LDS layout (bytes) ----
#define OFF_H     0        // h local tile: [16][72] u16 = 2304
#define OFF_PRE   2304     // pre: 7 gates * 16 * 72 u16 = 16128
#define OFF_G     18432    // gates: 7 * 16 * 68 f32 = 30464
#define OFF_XC    48896    // xc table: 7 * 64 * 13 f32 = 23296
#define OFF_B2    72192    // g_b2 slice: 7*64 f32 = 1792
#define OFF_IW    73984    // i_W slice: 64 f32 = 256
#define OFF_X12   74240    // x12: 12*64 f32 = 3072
#define OFF_IDXA  77312    // idx_all: 511*16 u8 -> 8192
#define OFF_DTA   85504    // dt_all: 511*16 f32 = 32704
#define SMEM_BYTES 118208

__device__ __forceinline__ u16 f2bf(float f) {
  unsigned u = __float_as_uint(f);
  u += 0x7FFFu + ((u >> 16) & 1u);  // round-to-nearest-even
  return (u16)(u >> 16);
}
__device__ __forceinline__ float sigm(float x) { return 1.0f / (1.0f + __expf(-x)); }
__device__ __forceinline__ float tanh_fast(float x) {
  float e = __expf(2.0f * x);
  return 1.0f - 2.0f / (e + 1.0f);   // NaN-free: x->+inf => 1, x->-inf => -1
}
__device__ __forceinline__ float softplus_f(float x) {
  return fmaxf(x, 0.0f) + __logf(1.0f + __expf(-fabsf(x)));
}
__device__ __forceinline__ int ald(const int* p) {
  return __hip_atomic_load(p, __ATOMIC_RELAXED, __HIP_MEMORY_SCOPE_AGENT);
}
__device__ __forceinline__ u64 ald64(const u64* p) {
  return __hip_atomic_load(p, __ATOMIC_RELAXED, __HIP_MEMORY_SCOPE_AGENT);
}

// ---------------- prep: 12 embeddings, zero h buf0, reset barrier flags ----------------
__global__ void ct4_prep(const float* __restrict__ etW1, const float* __restrict__ etb1,
                         const float* __restrict__ etW2, const float* __restrict__ etb2,
                         const float* __restrict__ esW1, const float* __restrict__ esb1,
                         const float* __restrict__ esW2, const float* __restrict__ esb2,
                         char* __restrict__ ws) {
  __shared__ float sT[4][64];
  __shared__ float sS[3][64];
  const int i = threadIdx.x;  // 64 threads
  #pragma unroll
  for (int e = 0; e < 4; ++e) sT[e][i] = tanhf(etW1[i * 4 + e] + etb1[i]);
  #pragma unroll
  for (int s = 0; s < 3; ++s) sS[s][i] = tanhf(esW1[i * 3 + s] + esb1[i]);
  __syncthreads();
  float te[4], se[3];
  #pragma unroll
  for (int e = 0; e < 4; ++e) {
    float a = etb2[i];
    for (int jj = 0; jj < 64; ++jj) a += sT[e][jj] * etW2[i * 64 + jj];
    te[e] = tanhf(a);
  }
  #pragma unroll
  for (int s = 0; s < 3; ++s) {
    float a = esb2[i];
    for (int jj = 0; jj < 64; ++jj) a += sS[s][jj] * esW2[i * 64 + jj];
    se[s] = tanhf(a);
  }
  float* x12 = (float*)(ws + WS_X12);
  #pragma unroll
  for (int e = 0; e < 4; ++e)
    #pragma unroll
    for (int s = 0; s < 3; ++s) x12[(e * 3 + s) * 64 + i] = te[e] + se[s];
  // zero h buffer 0
  u32x4* hz = (u32x4*)(ws + WS_HBUF);
  u32x4 z = {0u, 0u, 0u, 0u};
  for (int p = i; p < 65536 / 16; p += 64) hz[p] = z;
  // reset barrier flags
  int* bars = (int*)(ws + WS_BAR);
  for (int p = i; p < 1024; p += 64) bars[p] = 0;
}

// ---------------- main persistent recurrence kernel ----------------
// grid: 32 blocks x 512 threads. block (grp = bid&7, j = bid>>3): batch rows
// [grp*16, grp*16+16), hidden block j (64 units). Wave k (0..6) owns gate k; wave 7
// helps phase C / output stores only. Per step: 2 __syncthreads. Remote h goes
// DIRECTLY global->registers per wave (no LDS staging, no dedicated puller):
// each wave polls partner flags at the loop bottom and issues its 12 x 8B agent
// loads, which complete under the loop tail + next-top scheduling.
__global__ __launch_bounds__(512, 1) void ct4_main(
    const int* __restrict__ ev, const float* __restrict__ ts, const int* __restrict__ mk,
    const float* __restrict__ gW1, const float* __restrict__ gb1,
    const float* __restrict__ gW2, const float* __restrict__ gb2,
    const float* __restrict__ iW, const float* __restrict__ ibp,
    float* __restrict__ out, char* __restrict__ ws) {
  extern __shared__ char smem[];
  u16* h_lds = (u16*)(smem + OFF_H);          // [16][72] (local 64 cols + pad)
  float* g_lds = (float*)(smem + OFF_G);      // [7][16][68]
  float* xc_lds = (float*)(smem + OFF_XC);    // [(k*64+o)*13 + m]
  float* b2_lds = (float*)(smem + OFF_B2);    // [7][64]
  float* iw_lds = (float*)(smem + OFF_IW);    // [64]
  float* x12_lds = (float*)(smem + OFF_X12);  // [12][64]
  u8* idx_all = (u8*)(smem + OFF_IDXA);       // [511*16]
  float* dt_all = (float*)(smem + OFF_DTA);   // [511*16]

  const int tid = threadIdx.x;
  const int bid = blockIdx.x;
  const int grp = bid & 7;
  const int j = bid >> 3;
  const int b0 = grp * MBQ;
  const int wave = tid >> 6;     // 0..7
  const int q = (tid >> 4) & 3;
  const int c = tid & 15;
  const int kloc0 = 2 * j;       // local K tiles (32-wide) are {2j, 2j+1}
  const int k = wave;            // gate owned by this wave (wave<7)

  u16* hbuf = (u16*)(ws + WS_HBUF);
  int* bars = (int*)(ws + WS_BAR);
  int* myflag = bars + grp * 128 + j * 32;
  int* f0p = bars + grp * 128 + (0 + (0 >= j)) * 32;
  int* f1p = bars + grp * 128 + (1 + (1 >= j)) * 32;
  int* f2p = bars + grp * 128 + (2 + (2 >= j)) * 32;

  // ---- prologue ----
  for (int p = tid; p < 12 * 64; p += 512) x12_lds[p] = ((const float*)(ws + WS_X12))[p];
  for (int p = tid; p < 16 * 72 * 2 / 4; p += 512) ((unsigned*)h_lds)[p] = 0u;  // h(0)=0
  if (tid < 448) {
    int kk = tid >> 6, o = tid & 63;
    b2_lds[kk * 64 + o] = gb2[kk * 256 + j * 64 + o];
  }
  if (tid < 64) iw_lds[tid] = iW[j * 256 + j * 64 + tid];
  const float ibj = ibp[j];
  for (int p = tid; p < STEPS * 16; p += 512) {
    int t = p >> 4, b = p & 15;
    idx_all[p] = (u8)(ev[(b0 + b) * NT + t] * 3 + mk[(b0 + b) * NT + t]);
    dt_all[p] = ts[(b0 + b) * NT + t + 1];
  }
  __syncthreads();
  // xc table: xc[k][o][m] = g_b1[k][j*64+o] + sum_i x12[m][i] * W1[k][j*64+o][i]
  if (tid < 448) {
    int kk = tid >> 6, o = tid & 63;
    const float* row = gW1 + (size_t)(kk * 256 + j * 64 + o) * 320;
    float a[12];
    float bb = gb1[kk * 256 + j * 64 + o];
    #pragma unroll
    for (int m = 0; m < 12; ++m) a[m] = bb;
    for (int i = 0; i < 64; ++i) {
      float w = row[i];
      #pragma unroll
      for (int m = 0; m < 12; ++m) a[m] += x12_lds[m * 64 + i] * w;
    }
    #pragma unroll
    for (int m = 0; m < 12; ++m) xc_lds[(kk * 64 + o) * 13 + m] = a[m];
  }

  // weight fragments (bf16). Slot order: s=0..5 remote K tiles (kt = s + (s>=2j ? 2:0)),
  // s=6..7 local K tiles (kt = 2j, 2j+1). One gate per wave.
  s16x8 a1[4][8];  // W1 h-part: M=64 (o), K=256 (h)
  s16x8 a2[4][2];  // W2 block:  M=64 (o), K=64 (g)
  if (wave < 7) {
    #pragma unroll
    for (int s = 0; s < 8; ++s) {
      int kt = (s < 6) ? (s + (s >= kloc0 ? 2 : 0)) : (kloc0 + (s - 6));
      #pragma unroll
      for (int mt = 0; mt < 4; ++mt) {
        const float* p = gW1 + (size_t)(k * 256 + j * 64 + 16 * mt + c) * 320 + 64 + 32 * kt + 8 * q;
        union { s16x8 v; u16 u[8]; } fr;
        #pragma unroll
        for (int i = 0; i < 8; ++i) fr.u[i] = f2bf(p[i]);
        a1[mt][s] = fr.v;
      }
    }
    #pragma unroll
    for (int mt = 0; mt < 4; ++mt)
      #pragma unroll
      for (int kt = 0; kt < 2; ++kt) {
        const float* p = gW2 + (size_t)(k * 256 + j * 64 + 16 * mt + c) * 256 + j * 64 + 32 * kt + 8 * q;
        union { s16x8 v; u16 u[8]; } fr;
        #pragma unroll
        for (int i = 0; i < 8; ++i) fr.u[i] = f2bf(p[i]);
        a2[mt][kt] = fr.v;
      }
  }

  float ccA[2] = {0.f, 0.f};   // c state (2 elems per thread)
  float cctA[2] = {0.f, 0.f};  // c_target state
  f32x4 acc[4] = {};           // GEMM1 accumulator (local tiles pre-accumulated at bottom)
  union RB { s16x8 v; u64 d[2]; };
  RB rbf[6];                   // remote h B-fragments (loaded at loop bottom)
  #pragma unroll
  for (int s = 0; s < 6; ++s) { rbf[s].d[0] = 0ull; rbf[s].d[1] = 0ull; }  // h(0)=0
  const f32x4 fzero = {};
  __syncthreads();

  const int O_CELL = NB * STEPS * 4;
  const int SZB = NB * STEPS * NH;
  const int O_CT = O_CELL + SZB;
  const int O_OUT = O_CT + SZB;
  const int O_DEC = O_OUT + SZB;

  for (int t = 0; t < STEPS; ++t) {
    // ---- top: GEMM1 remote tiles (B-frags already in regs), tanh, GEMM2 ----
    if (wave < 7) {
      #pragma unroll
      for (int s = 0; s < 6; ++s)
        #pragma unroll
        for (int mt = 0; mt < 4; ++mt)
          acc[mt] = __builtin_amdgcn_mfma_f32_16x16x32_bf16(a1[mt][s], rbf[s].v, acc[mt], 0, 0, 0);
      u16* preW = (u16*)(smem + OFF_PRE) + k * (16 * 72);
      int midx = (int)idx_all[t * 16 + c];
      #pragma unroll
      for (int mt = 0; mt < 4; ++mt) {
        int o = 16 * mt + 4 * q;
        const float* xr = &xc_lds[(k * 64 + o) * 13 + midx];
        u16 u0 = f2bf(tanh_fast(acc[mt][0] + xr[0]));
        u16 u1 = f2bf(tanh_fast(acc[mt][1] + xr[13]));
        u16 u2 = f2bf(tanh_fast(acc[mt][2] + xr[26]));
        u16 u3 = f2bf(tanh_fast(acc[mt][3] + xr[39]));
        u32x2 pk;
        pk[0] = (unsigned)u0 | ((unsigned)u1 << 16);
        pk[1] = (unsigned)u2 | ((unsigned)u3 << 16);
        *(u32x2*)&preW[c * 72 + o] = pk;  // pre[b=c][o..o+3], bf16
      }
      f32x4 acc2[4] = {};
      #pragma unroll
      for (int kt = 0; kt < 2; ++kt) {
        s16x8 pf = *(const s16x8*)&preW[c * 72 + 32 * kt + 8 * q];
        #pragma unroll
        for (int mt = 0; mt < 4; ++mt)
          acc2[mt] = __builtin_amdgcn_mfma_f32_16x16x32_bf16(a2[mt][kt], pf, acc2[mt], 0, 0, 0);
      }
      #pragma unroll
      for (int mt = 0; mt < 4; ++mt)
        *(f32x4*)&g_lds[(k * 16 + c) * 68 + 16 * mt + 4 * q] = acc2[mt];
    }
    __syncthreads();  // sync1: g_lds ready

    // ---- phase C: gates, cell update, h_new (512 threads x 2 elems) ----
    const int b = tid >> 5, o2 = (tid & 31) * 2;
    float ip = 0.f;
    float ci[2], ctn[2], opv[2], dcv[2];
    {
      float dtv = dt_all[t * 16 + b];
      float G[7][2];
      #pragma unroll
      for (int kk = 0; kk < 7; ++kk) {
        f32x2 gg = *(const f32x2*)&g_lds[(kk * 16 + b) * 68 + o2];
        G[kk][0] = gg[0] + b2_lds[kk * 64 + o2];
        G[kk][1] = gg[1] + b2_lds[kk * 64 + o2 + 1];
      }
      float hnv[2];
      #pragma unroll
      for (int e = 0; e < 2; ++e) {
        float inp = sigm(G[0][e]);
        float fg = sigm(G[1][e]);
        float op = sigm(G[2][e]);
        float itg = sigm(G[3][e]);
        float ftg = sigm(G[4][e]);
        float z = tanh_fast(G[5][e]);
        float dc = softplus_f(G[6][e]);
        float c_i = fg * ccA[e] + inp * z;
        float c_t = ftg * cctA[e] + itg * z;
        float edv = __expf(-dc * dtv);
        float c_n = c_t + (c_i - c_t) * edv;
        float h_n = op * tanh_fast(c_n);
        ccA[e] = c_n;
        cctA[e] = c_t;
        ci[e] = c_i; ctn[e] = c_t; opv[e] = op; dcv[e] = dc;
        hnv[e] = h_n;
        ip += iw_lds[o2 + e] * h_n;
      }
      if (t < STEPS - 1) {
        unsigned hp = (unsigned)f2bf(hnv[0]) | ((unsigned)f2bf(hnv[1]) << 16);
        *(unsigned*)&h_lds[b * 72 + o2] = hp;  // local columns of h(t+1)
        __hip_atomic_store((unsigned*)&hbuf[((size_t)(((t + 1) & 1) * GQ + grp) * MBQ + b) * 256 + j * 64 + o2],
                           hp, __ATOMIC_RELAXED, __HIP_MEMORY_SCOPE_AGENT);
      }
    }
    __syncthreads();  // sync2: drains h stores (vmcnt 0) + orders h_lds writes

    if (tid == 0 && t < STEPS - 1)
      __hip_atomic_store(myflag, t + 1, __ATOMIC_RELAXED, __HIP_MEMORY_SCOPE_AGENT);

    // ---- bottom ----
    if (t < STEPS - 1) {
      // local K tiles of h(t+1) from LDS (available now)
      if (wave < 7) {
        s16x8 bfl0 = *(const s16x8*)&h_lds[c * 72 + 8 * q];
        s16x8 bfl1 = *(const s16x8*)&h_lds[c * 72 + 32 + 8 * q];
        #pragma unroll
        for (int mt = 0; mt < 4; ++mt)
          acc[mt] = __builtin_amdgcn_mfma_f32_16x16x32_bf16(a1[mt][6], bfl0, fzero, 0, 0, 0);
        #pragma unroll
        for (int mt = 0; mt < 4; ++mt)
          acc[mt] = __builtin_amdgcn_mfma_f32_16x16x32_bf16(a1[mt][7], bfl1, acc[mt], 0, 0, 0);
      }
      // output stores overlap the flag round trip
      {
        size_t base = ((size_t)(b0 + b) * STEPS + t) * NH + j * 64 + o2;
        f32x2 v;
        v[0] = ci[0];  v[1] = ci[1];  __builtin_nontemporal_store(v, (f32x2*)&out[O_CELL + base]);
        v[0] = ctn[0]; v[1] = ctn[1]; __builtin_nontemporal_store(v, (f32x2*)&out[O_CT + base]);
        v[0] = opv[0]; v[1] = opv[1]; __builtin_nontemporal_store(v, (f32x2*)&out[O_OUT + base]);
        v[0] = dcv[0]; v[1] = dcv[1]; __builtin_nontemporal_store(v, (f32x2*)&out[O_DEC + base]);
        #pragma unroll
        for (int d = 1; d < 32; d <<= 1) ip += __shfl_xor(ip, d, 32);
        if ((tid & 31) == 0)
          __builtin_nontemporal_store(softplus_f(ip + ibj),
                                      &out[((size_t)(b0 + b) * STEPS + t) * 4 + j]);
      }
      // each gate-wave polls partner flags and pulls its own remote B-fragments
      if (wave < 7) {
        for (;;) {
          int f0 = ald(f0p), f1 = ald(f1p), f2 = ald(f2p);
          if (f0 > t && f1 > t && f2 > t) break;
          __builtin_amdgcn_s_sleep(1);
        }
        const u16* hb = hbuf + ((size_t)(((t + 1) & 1) * GQ + grp) * MBQ + c) * 256 + 8 * q;
        #pragma unroll
        for (int s = 0; s < 6; ++s) {
          int ks = s + (s >= kloc0 ? 2 : 0);
          const u64* src = (const u64*)(hb + ks * 32);
          rbf[s].d[0] = ald64(src);
          rbf[s].d[1] = ald64(src + 1);
        }
      }
    } else {
      size_t base = ((size_t)(b0 + b) * STEPS + t) * NH + j * 64 + o2;
      f32x2 v;
      v[0] = ci[0];  v[1] = ci[1];  __builtin_nontemporal_store(v, (f32x2*)&out[O_CELL + base]);
      v[0] = ctn[0]; v[1] = ctn[1]; __builtin_nontemporal_store(v, (f32x2*)&out[O_CT + base]);
      v[0] = opv[0]; v[1] = opv[1]; __builtin_nontemporal_store(v, (f32x2*)&out[O_OUT + base]);
      v[0] = dcv[0]; v[1] = dcv[1]; __builtin_nontemporal_store(v, (f32x2*)&out[O_DEC + base]);
      #pragma unroll
      for (int d = 1; d < 32; d <<= 1) ip += __shfl_xor(ip, d, 32);
      if ((tid & 31) == 0)
        __builtin_nontemporal_store(softplus_f(ip + ibj),
                                    &out[((size_t)(b0 + b) * STEPS + t) * 4 + j]);
    }
  }
}

extern "C" void kernel_launch(void* const* d_in, const int* in_sizes, int n_in,
                              void* d_out, int out_size, void* d_ws, size_t ws_size,
                              hipStream_t stream) {
  const int* ev = (const int*)d_in[0];
  const float* ts = (const float*)d_in[1];
  const int* mk = (const int*)d_in[2];
  const float* etW1 = (const float*)d_in[3];
  const float* etb1 = (const float*)d_in[4];
  const float* etW2 = (const float*)d_in[5];
  const float* etb2 = (const float*)d_in[6];
  const float* esW1 = (const float*)d_in[7];
  const float* esb1 = (const float*)d_in[8];
  const float* esW2 = (const float*)d_in[9];
  const float* esb2 = (const float*)d_in[10];
  const float* gW1 = (const float*)d_in[11];
  const float* gb1 = (const float*)d_in[12];
  const float* gW2 = (const float*)d_in[13];
  const float* gb2 = (const float*)d_in[14];
  const float* iW = (const float*)d_in[15];
  const float* ibv = (const float*)d_in[16];
  char* ws = (char*)d_ws;
  float* out = (float*)d_out;

  ct4_prep<<<1, 64, 0, stream>>>(etW1, etb1, etW2, etb2, esW1, esb1, esW2, esb2, ws);
  (void)hipFuncSetAttribute((const void*)ct4_main,
                            hipFuncAttributeMaxDynamicSharedMemorySize, SMEM_BYTES);
  ct4_main<<<GQ * 4, 512, SMEM_BYTES, stream>>>(ev, ts, mk, gW1, gb1, gW2, gb2, iW, ibv, out, ws);
}

// Round 8
// 2165.878 us; speedup vs baseline: 1.5172x; 1.5172x over previous
//
#include <hip/hip_runtime.h>
#include <stdint.h>

typedef unsigned short u16;
typedef unsigned char u8;
typedef unsigned long long u64;
typedef short s16x8 __attribute__((ext_vector_type(8)));
typedef float f32x4 __attribute__((ext_vector_type(4)));
typedef float f32x2 __attribute__((ext_vector_type(2)));
typedef unsigned int u32x4 __attribute__((ext_vector_type(4)));
typedef unsigned int u32x2 __attribute__((ext_vector_type(2)));

#define NB 128
#define NT 512
#define NH 256
#define GQ 8      // batch groups
#define MBQ 16    // batch rows per group
#define STEPS 511

// ---- workspace layout (bytes) ----
#define WS_HBUF 0        // double-buffered h: 2 * GQ * MBQ * 256 * 2B = 131072
#define WS_X12  131072   // 12*64 floats = 3072
#define WS_BAR  134144   // 8 groups * 4 flags * 128B = 4096

// ---- dynamic LDS layout (bytes) ----
#define OFF_H     0        // h tile:   16 rows * 264 u16 = 8448
#define OFF_PRE   8448     // pre:      7 gates * 16 * 72 u16 = 16128
#define OFF_G     24576    // gates:    7 * 16 * 68 f32 = 30464
#define OFF_XC    55040    // xc table: 7 * 64 * 13 f32 = 23296
#define OFF_B2    78336    // g_b2 slice: 7*64 f32 = 1792
#define OFF_IW    80128    // i_W slice: 64 f32 = 256
#define OFF_X12   80384    // x12: 12*64 f32 = 3072
#define OFF_IDXA  83456    // idx_all: 511*16 u8 -> 8192
#define OFF_DTA   91648    // dt_all: 511*16 f32 = 32704
#define SMEM_BYTES 124416

__device__ __forceinline__ u16 f2bf(float f) {
  unsigned u = __float_as_uint(f);
  u += 0x7FFFu + ((u >> 16) & 1u);  // round-to-nearest-even
  return (u16)(u >> 16);
}
__device__ __forceinline__ float sigm(float x) { return 1.0f / (1.0f + __expf(-x)); }
__device__ __forceinline__ float tanh_fast(float x) {
  float e = __expf(2.0f * x);
  return 1.0f - 2.0f / (e + 1.0f);   // NaN-free: x->+inf => 1, x->-inf => -1
}
__device__ __forceinline__ float softplus_f(float x) {
  return fmaxf(x, 0.0f) + __logf(1.0f + __expf(-fabsf(x)));
}

// ---------------- prep: 12 embeddings, zero h buf0, reset barrier flags ----------------
__global__ void ct4_prep(const float* __restrict__ etW1, const float* __restrict__ etb1,
                         const float* __restrict__ etW2, const float* __restrict__ etb2,
                         const float* __restrict__ esW1, const float* __restrict__ esb1,
                         const float* __restrict__ esW2, const float* __restrict__ esb2,
                         char* __restrict__ ws) {
  __shared__ float sT[4][64];
  __shared__ float sS[3][64];
  const int i = threadIdx.x;  // 64 threads
  #pragma unroll
  for (int e = 0; e < 4; ++e) sT[e][i] = tanhf(etW1[i * 4 + e] + etb1[i]);
  #pragma unroll
  for (int s = 0; s < 3; ++s) sS[s][i] = tanhf(esW1[i * 3 + s] + esb1[i]);
  __syncthreads();
  float te[4], se[3];
  #pragma unroll
  for (int e = 0; e < 4; ++e) {
    float a = etb2[i];
    for (int jj = 0; jj < 64; ++jj) a += sT[e][jj] * etW2[i * 64 + jj];
    te[e] = tanhf(a);
  }
  #pragma unroll
  for (int s = 0; s < 3; ++s) {
    float a = esb2[i];
    for (int jj = 0; jj < 64; ++jj) a += sS[s][jj] * esW2[i * 64 + jj];
    se[s] = tanhf(a);
  }
  float* x12 = (float*)(ws + WS_X12);
  #pragma unroll
  for (int e = 0; e < 4; ++e)
    #pragma unroll
    for (int s = 0; s < 3; ++s) x12[(e * 3 + s) * 64 + i] = te[e] + se[s];
  // zero h buffer 0 (first 65536 bytes of WS_HBUF)
  u32x4* hz = (u32x4*)(ws + WS_HBUF);
  u32x4 z = {0u, 0u, 0u, 0u};
  for (int p = i; p < 65536 / 16; p += 64) hz[p] = z;
  // reset barrier flags (8 groups * 4 flags * 32-int stride)
  int* bars = (int*)(ws + WS_BAR);
  for (int p = i; p < 1024; p += 64) bars[p] = 0;
}

// ---------------- main persistent recurrence kernel ----------------
// r3 structure (verified 2230us): 32 blocks x 512 threads; block (grp = bid&7, j = bid>>3);
// wave k (0..6) owns gate k, wave 7 pulls remote h. Relaxed agent-scope exchange.
// ONLY change vs r3: output stores are NORMAL stores (L2-backed), not nontemporal.
// With no release/acquire fences in the loop, L2 dirtiness is harmless, and store acks
// come from L2 -> the per-step barrier no longer waits on an HBM write drain.
__global__ __launch_bounds__(512, 1) void ct4_main(
    const int* __restrict__ ev, const float* __restrict__ ts, const int* __restrict__ mk,
    const float* __restrict__ gW1, const float* __restrict__ gb1,
    const float* __restrict__ gW2, const float* __restrict__ gb2,
    const float* __restrict__ iW, const float* __restrict__ ibp,
    float* __restrict__ out, char* __restrict__ ws) {
  extern __shared__ char smem[];
  u16* h_lds = (u16*)(smem + OFF_H);          // [16][264]
  float* g_lds = (float*)(smem + OFF_G);      // [7][16][68]
  float* xc_lds = (float*)(smem + OFF_XC);    // [(k*64+o)*13 + m]
  float* b2_lds = (float*)(smem + OFF_B2);    // [7][64]
  float* iw_lds = (float*)(smem + OFF_IW);    // [64]
  float* x12_lds = (float*)(smem + OFF_X12);  // [12][64]
  u8* idx_all = (u8*)(smem + OFF_IDXA);       // [511*16]
  float* dt_all = (float*)(smem + OFF_DTA);   // [511*16]

  const int tid = threadIdx.x;
  const int bid = blockIdx.x;
  const int grp = bid & 7;
  const int j = bid >> 3;
  const int b0 = grp * MBQ;
  const int wave = tid >> 6;
  const int q = (tid >> 4) & 3;
  const int c = tid & 15;
  const int kloc0 = 2 * j;  // local K tiles (32-wide) are {2j, 2j+1}

  u16* hbuf = (u16*)(ws + WS_HBUF);
  int* bars = (int*)(ws + WS_BAR);
  int* myflag = bars + grp * 128 + j * 32;

  // ---- prologue ----
  for (int p = tid; p < 12 * 64; p += 512) x12_lds[p] = ((const float*)(ws + WS_X12))[p];
  for (int p = tid; p < 16 * 264 / 2; p += 512) ((unsigned*)h_lds)[p] = 0u;  // h(0)=0
  if (tid < 448) {
    int kk = tid >> 6, o = tid & 63;
    b2_lds[kk * 64 + o] = gb2[kk * 256 + j * 64 + o];
  }
  if (tid < 64) iw_lds[tid] = iW[j * 256 + j * 64 + tid];
  const float ibj = ibp[j];
  // preload all per-step indices / dts into LDS
  for (int p = tid; p < STEPS * 16; p += 512) {
    int t = p >> 4, b = p & 15;
    idx_all[p] = (u8)(ev[(b0 + b) * NT + t] * 3 + mk[(b0 + b) * NT + t]);
    dt_all[p] = ts[(b0 + b) * NT + t + 1];
  }
  __syncthreads();
  // xc table: xc[k][o][m] = g_b1[k][j*64+o] + sum_i x12[m][i] * W1[k][j*64+o][i]
  if (tid < 448) {
    int kk = tid >> 6, o = tid & 63;
    const float* row = gW1 + (size_t)(kk * 256 + j * 64 + o) * 320;
    float a[12];
    float bb = gb1[kk * 256 + j * 64 + o];
    #pragma unroll
    for (int m = 0; m < 12; ++m) a[m] = bb;
    for (int i = 0; i < 64; ++i) {
      float w = row[i];
      #pragma unroll
      for (int m = 0; m < 12; ++m) a[m] += x12_lds[m * 64 + i] * w;
    }
    #pragma unroll
    for (int m = 0; m < 12; ++m) xc_lds[(kk * 64 + o) * 13 + m] = a[m];
  }

  // weight fragments (register-resident where the allocator allows, bf16).
  // Slot order: s=0..5 remote K tiles (kt = s + (s >= 2j ? 2 : 0)), s=6..7 local tiles.
  s16x8 a1[4][8];  // W1 h-part: M=64 (o), K=256 (h)
  s16x8 a2[4][2];  // W2 block:  M=64 (o), K=64 (g)
  const int k = wave;
  if (wave < 7) {
    #pragma unroll
    for (int s = 0; s < 8; ++s) {
      int kt = (s < 6) ? (s + (s >= kloc0 ? 2 : 0)) : (kloc0 + (s - 6));
      #pragma unroll
      for (int mt = 0; mt < 4; ++mt) {
        const float* p = gW1 + (size_t)(k * 256 + j * 64 + 16 * mt + c) * 320 + 64 + 32 * kt + 8 * q;
        union { s16x8 v; u16 u[8]; } fr;
        #pragma unroll
        for (int i = 0; i < 8; ++i) fr.u[i] = f2bf(p[i]);
        a1[mt][s] = fr.v;
      }
    }
    #pragma unroll
    for (int mt = 0; mt < 4; ++mt)
      #pragma unroll
      for (int kt = 0; kt < 2; ++kt) {
        const float* p = gW2 + (size_t)(k * 256 + j * 64 + 16 * mt + c) * 256 + j * 64 + 32 * kt + 8 * q;
        union { s16x8 v; u16 u[8]; } fr;
        #pragma unroll
        for (int i = 0; i < 8; ++i) fr.u[i] = f2bf(p[i]);
        a2[mt][kt] = fr.v;
      }
  }

  float ccA[2] = {0.f, 0.f};   // c state
  float cctA[2] = {0.f, 0.f};  // c_target state
  f32x4 acc[4] = {};           // GEMM1 accumulator (local tiles pre-accumulated at bottom)
  const f32x4 fzero = {};
  __syncthreads();

  const int O_CELL = NB * STEPS * 4;
  const int SZB = NB * STEPS * NH;
  const int O_CT = O_CELL + SZB;
  const int O_OUT = O_CT + SZB;
  const int O_DEC = O_OUT + SZB;

  for (int t = 0; t < STEPS; ++t) {
    // ---- top: GEMM1 remote tiles, tanh, GEMM2 ----
    if (wave < 7) {
      #pragma unroll
      for (int s = 0; s < 6; ++s) {
        int ks = s + (s >= kloc0 ? 2 : 0);
        s16x8 bf = *(const s16x8*)&h_lds[c * 264 + 32 * ks + 8 * q];
        #pragma unroll
        for (int mt = 0; mt < 4; ++mt)
          acc[mt] = __builtin_amdgcn_mfma_f32_16x16x32_bf16(a1[mt][s], bf, acc[mt], 0, 0, 0);
      }
      u16* preW = (u16*)(smem + OFF_PRE) + k * (16 * 72);
      int midx = (int)idx_all[t * 16 + c];
      #pragma unroll
      for (int mt = 0; mt < 4; ++mt) {
        int o = 16 * mt + 4 * q;
        const float* xr = &xc_lds[(k * 64 + o) * 13 + midx];
        u16 u0 = f2bf(tanh_fast(acc[mt][0] + xr[0]));
        u16 u1 = f2bf(tanh_fast(acc[mt][1] + xr[13]));
        u16 u2 = f2bf(tanh_fast(acc[mt][2] + xr[26]));
        u16 u3 = f2bf(tanh_fast(acc[mt][3] + xr[39]));
        u32x2 pk;
        pk[0] = (unsigned)u0 | ((unsigned)u1 << 16);
        pk[1] = (unsigned)u2 | ((unsigned)u3 << 16);
        *(u32x2*)&preW[c * 72 + o] = pk;  // pre[b=c][o..o+3], bf16
      }
      f32x4 acc2[4] = {};
      #pragma unroll
      for (int kt = 0; kt < 2; ++kt) {
        s16x8 pf = *(const s16x8*)&preW[c * 72 + 32 * kt + 8 * q];
        #pragma unroll
        for (int mt = 0; mt < 4; ++mt)
          acc2[mt] = __builtin_amdgcn_mfma_f32_16x16x32_bf16(a2[mt][kt], pf, acc2[mt], 0, 0, 0);
      }
      #pragma unroll
      for (int mt = 0; mt < 4; ++mt)
        *(f32x4*)&g_lds[(k * 16 + c) * 68 + 16 * mt + 4 * q] = acc2[mt];
    }
    __syncthreads();

    // ---- phase C: gates, cell update, h_new ----
    const int b = tid >> 5, o2 = (tid & 31) * 2;
    float ip = 0.f;
    float ci[2], ctn[2], opv[2], dcv[2];
    {
      float dtv = dt_all[t * 16 + b];
      float G[7][2];
      #pragma unroll
      for (int kk = 0; kk < 7; ++kk) {
        f32x2 gg = *(const f32x2*)&g_lds[(kk * 16 + b) * 68 + o2];
        G[kk][0] = gg[0] + b2_lds[kk * 64 + o2];
        G[kk][1] = gg[1] + b2_lds[kk * 64 + o2 + 1];
      }
      float hnv[2];
      #pragma unroll
      for (int e = 0; e < 2; ++e) {
        float inp = sigm(G[0][e]);
        float fg = sigm(G[1][e]);
        float op = sigm(G[2][e]);
        float itg = sigm(G[3][e]);
        float ftg = sigm(G[4][e]);
        float z = tanh_fast(G[5][e]);
        float dc = softplus_f(G[6][e]);
        float c_i = fg * ccA[e] + inp * z;
        float c_t = ftg * cctA[e] + itg * z;
        float edv = __expf(-dc * dtv);
        float c_n = c_t + (c_i - c_t) * edv;
        float h_n = op * tanh_fast(c_n);
        ccA[e] = c_n;
        cctA[e] = c_t;
        ci[e] = c_i; ctn[e] = c_t; opv[e] = op; dcv[e] = dc;
        hnv[e] = h_n;
        ip += iw_lds[o2 + e] * h_n;
      }
      unsigned hp = (unsigned)f2bf(hnv[0]) | ((unsigned)f2bf(hnv[1]) << 16);
      if (t < STEPS - 1) {
        *(unsigned*)&h_lds[b * 264 + j * 64 + o2] = hp;  // local columns of h(t+1)
        __hip_atomic_store((unsigned*)&hbuf[((size_t)(((t + 1) & 1) * GQ + grp) * MBQ + b) * 256 + j * 64 + o2],
                           hp, __ATOMIC_RELAXED, __HIP_MEMORY_SCOPE_AGENT);
      }
    }
    __syncthreads();  // drains h stores (vmcnt 0) + orders h_lds local writes

    // ---- arrive: publish own flag ----
    if (tid == 0 && t < STEPS - 1)
      __hip_atomic_store(myflag, t + 1, __ATOMIC_RELAXED, __HIP_MEMORY_SCOPE_AGENT);

    // C2: output stores + intensity (L2-backed normal stores; ack fast, writeback async)
    auto C2 = [&]() {
      size_t base = ((size_t)(b0 + b) * STEPS + t) * NH + j * 64 + o2;
      f32x2 v;
      v[0] = ci[0];  v[1] = ci[1];  *(f32x2*)&out[O_CELL + base] = v;
      v[0] = ctn[0]; v[1] = ctn[1]; *(f32x2*)&out[O_CT + base] = v;
      v[0] = opv[0]; v[1] = opv[1]; *(f32x2*)&out[O_OUT + base] = v;
      v[0] = dcv[0]; v[1] = dcv[1]; *(f32x2*)&out[O_DEC + base] = v;
      #pragma unroll
      for (int d = 1; d < 32; d <<= 1) ip += __shfl_xor(ip, d, 32);
      if ((tid & 31) == 0)
        out[((size_t)(b0 + b) * STEPS + t) * 4 + j] = softplus_f(ip + ibj);
    };

    if (t < STEPS - 1) {
      if (wave < 7) {
        // GEMM1 local tiles of h(t+1) while wave 7 fetches remote h
        #pragma unroll
        for (int mt = 0; mt < 4; ++mt) acc[mt] = fzero;
        #pragma unroll
        for (int s = 6; s < 8; ++s) {
          int ks = kloc0 + (s - 6);
          s16x8 bf = *(const s16x8*)&h_lds[c * 264 + 32 * ks + 8 * q];
          #pragma unroll
          for (int mt = 0; mt < 4; ++mt)
            acc[mt] = __builtin_amdgcn_mfma_f32_16x16x32_bf16(a1[mt][s], bf, acc[mt], 0, 0, 0);
        }
        C2();
      } else {
        C2();
        // wave 7: poll remote flags, pull 3x2KB of remote h(t+1)
        const int l = tid & 63;
        const int row = l >> 2;
        const int segb = (l & 3) * 32;  // byte offset within the 128B row-chunk
        int* f0p = bars + grp * 128 + (0 + (0 >= j)) * 32;
        int* f1p = bars + grp * 128 + (1 + (1 >= j)) * 32;
        int* f2p = bars + grp * 128 + (2 + (2 >= j)) * 32;
        for (;;) {
          int f0 = __hip_atomic_load(f0p, __ATOMIC_RELAXED, __HIP_MEMORY_SCOPE_AGENT);
          int f1 = __hip_atomic_load(f1p, __ATOMIC_RELAXED, __HIP_MEMORY_SCOPE_AGENT);
          int f2 = __hip_atomic_load(f2p, __ATOMIC_RELAXED, __HIP_MEMORY_SCOPE_AGENT);
          if (f0 > t && f1 > t && f2 > t) break;
          __builtin_amdgcn_s_sleep(1);
        }
        const char* rbase = (const char*)hbuf +
            ((size_t)(((t + 1) & 1) * GQ + grp) * MBQ + row) * 512 + segb;
        u64 dv[3][4];
        #pragma unroll
        for (int rb = 0; rb < 3; ++rb) {
          int jr = rb + (rb >= j);
          const u64* src = (const u64*)(rbase + jr * 128);
          #pragma unroll
          for (int kq = 0; kq < 4; ++kq)
            dv[rb][kq] = __hip_atomic_load(src + kq, __ATOMIC_RELAXED, __HIP_MEMORY_SCOPE_AGENT);
        }
        char* lbase = (char*)h_lds + row * 528 + segb;
        #pragma unroll
        for (int rb = 0; rb < 3; ++rb) {
          int jr = rb + (rb >= j);
          #pragma unroll
          for (int kq = 0; kq < 4; ++kq)
            *(u64*)(lbase + jr * 128 + 8 * kq) = dv[rb][kq];
        }
      }
      __syncthreads();  // remote h_lds writes visible to all waves
    } else {
      C2();
    }
  }
}

extern "C" void kernel_launch(void* const* d_in, const int* in_sizes, int n_in,
                              void* d_out, int out_size, void* d_ws, size_t ws_size,
                              hipStream_t stream) {
  const int* ev = (const int*)d_in[0];
  const float* ts = (const float*)d_in[1];
  const int* mk = (const int*)d_in[2];
  const float* etW1 = (const float*)d_in[3];
  const float* etb1 = (const float*)d_in[4];
  const float* etW2 = (const float*)d_in[5];
  const float* etb2 = (const float*)d_in[6];
  const float* esW1 = (const float*)d_in[7];
  const float* esb1 = (const float*)d_in[8];
  const float* esW2 = (const float*)d_in[9];
  const float* esb2 = (const float*)d_in[10];
  const float* gW1 = (const float*)d_in[11];
  const float* gb1 = (const float*)d_in[12];
  const float* gW2 = (const float*)d_in[13];
  const float* gb2 = (const float*)d_in[14];
  const float* iW = (const float*)d_in[15];
  const float* ibv = (const float*)d_in[16];
  char* ws = (char*)d_ws;
  float* out = (float*)d_out;

  ct4_prep<<<1, 64, 0, stream>>>(etW1, etb1, etW2, etb2, esW1, esb1, esW2, esb2, ws);
  (void)hipFuncSetAttribute((const void*)ct4_main,
                            hipFuncAttributeMaxDynamicSharedMemorySize, SMEM_BYTES);
  ct4_main<<<GQ * 4, 512, SMEM_BYTES, stream>>>(ev, ts, mk, gW1, gb1, gW2, gb2, iW, ibv, out, ws);
}

// Round 9
// 2163.286 us; speedup vs baseline: 1.5190x; 1.0012x over previous
//
#include <hip/hip_runtime.h>
#include <stdint.h>

typedef unsigned short u16;
typedef unsigned char u8;
typedef unsigned long long u64;
typedef short s16x8 __attribute__((ext_vector_type(8)));
typedef float f32x4 __attribute__((ext_vector_type(4)));
typedef float f32x2 __attribute__((ext_vector_type(2)));
typedef unsigned int u32x4 __attribute__((ext_vector_type(4)));
typedef unsigned int u32x2 __attribute__((ext_vector_type(2)));

#define NB 128
#define NT 512
#define NH 256
#define GQ 8      // batch groups
#define MBQ 16    // batch rows per group
#define STEPS 511

// ---- workspace layout (bytes) ----
#define WS_HBUF 0        // double-buffered h: 2 * GQ * MBQ * 256 * 2B = 131072
#define WS_X12  131072   // 12*64 floats = 3072
#define WS_BAR  134144   // 8 groups * 4 flags * 128B = 4096

// ---- dynamic LDS layout (bytes) ----
#define OFF_H     0        // h tile:   16 rows * 264 u16 = 8448
#define OFF_PRE   8448     // pre:      7 gates * 16 * 72 u16 = 16128
#define OFF_G     24576    // gates:    7 * 16 * 68 f32 = 30464
#define OFF_XC    55040    // xc table: 7 * 64 * 13 f32 = 23296
#define OFF_B2    78336    // g_b2 slice: 7*64 f32 = 1792
#define OFF_IW    80128    // i_W slice: 64 f32 = 256
#define OFF_X12   80384    // x12: 12*64 f32 = 3072
#define OFF_IDXA  83456    // idx_all: 511*16 u8 -> 8192
#define OFF_DTA   91648    // dt_all: 511*16 f32 = 32704
#define SMEM_BYTES 124416

__device__ __forceinline__ u16 f2bf(float f) {
  unsigned u = __float_as_uint(f);
  u += 0x7FFFu + ((u >> 16) & 1u);  // round-to-nearest-even
  return (u16)(u >> 16);
}
__device__ __forceinline__ float sigm(float x) { return 1.0f / (1.0f + __expf(-x)); }
__device__ __forceinline__ float tanh_fast(float x) {
  float e = __expf(2.0f * x);
  return 1.0f - 2.0f / (e + 1.0f);   // NaN-free: x->+inf => 1, x->-inf => -1
}
__device__ __forceinline__ float softplus_f(float x) {
  return fmaxf(x, 0.0f) + __logf(1.0f + __expf(-fabsf(x)));
}

// ---------------- prep: 12 embeddings, zero h buf0, reset barrier flags ----------------
__global__ void ct4_prep(const float* __restrict__ etW1, const float* __restrict__ etb1,
                         const float* __restrict__ etW2, const float* __restrict__ etb2,
                         const float* __restrict__ esW1, const float* __restrict__ esb1,
                         const float* __restrict__ esW2, const float* __restrict__ esb2,
                         char* __restrict__ ws) {
  __shared__ float sT[4][64];
  __shared__ float sS[3][64];
  const int i = threadIdx.x;  // 64 threads
  #pragma unroll
  for (int e = 0; e < 4; ++e) sT[e][i] = tanhf(etW1[i * 4 + e] + etb1[i]);
  #pragma unroll
  for (int s = 0; s < 3; ++s) sS[s][i] = tanhf(esW1[i * 3 + s] + esb1[i]);
  __syncthreads();
  float te[4], se[3];
  #pragma unroll
  for (int e = 0; e < 4; ++e) {
    float a = etb2[i];
    for (int jj = 0; jj < 64; ++jj) a += sT[e][jj] * etW2[i * 64 + jj];
    te[e] = tanhf(a);
  }
  #pragma unroll
  for (int s = 0; s < 3; ++s) {
    float a = esb2[i];
    for (int jj = 0; jj < 64; ++jj) a += sS[s][jj] * esW2[i * 64 + jj];
    se[s] = tanhf(a);
  }
  float* x12 = (float*)(ws + WS_X12);
  #pragma unroll
  for (int e = 0; e < 4; ++e)
    #pragma unroll
    for (int s = 0; s < 3; ++s) x12[(e * 3 + s) * 64 + i] = te[e] + se[s];
  // zero h buffer 0 (first 65536 bytes of WS_HBUF)
  u32x4* hz = (u32x4*)(ws + WS_HBUF);
  u32x4 z = {0u, 0u, 0u, 0u};
  for (int p = i; p < 65536 / 16; p += 64) hz[p] = z;
  // reset barrier flags (8 groups * 4 flags * 32-int stride)
  int* bars = (int*)(ws + WS_BAR);
  for (int p = i; p < 1024; p += 64) bars[p] = 0;
}

// ---------------- main persistent recurrence kernel ----------------
// r8 structure (verified 2166us) with ONE change: amdgpu_waves_per_eu(2,2) pins the
// register budget at 256/wave (2 waves/SIMD, 512-reg pool), so the ~160 regs of weight
// fragments stay truly register-resident instead of being spilled/rematerialized from
// L2 every step (r3/r8 showed VGPR_Count=128 -> per-step weight re-load was the hidden
// ~2us/step). 32 blocks x 512 threads; wave k (0..6) owns gate k; wave 7 pulls remote h.
__global__ __launch_bounds__(512, 1)
__attribute__((amdgpu_waves_per_eu(2, 2))) void ct4_main(
    const int* __restrict__ ev, const float* __restrict__ ts, const int* __restrict__ mk,
    const float* __restrict__ gW1, const float* __restrict__ gb1,
    const float* __restrict__ gW2, const float* __restrict__ gb2,
    const float* __restrict__ iW, const float* __restrict__ ibp,
    float* __restrict__ out, char* __restrict__ ws) {
  extern __shared__ char smem[];
  u16* h_lds = (u16*)(smem + OFF_H);          // [16][264]
  float* g_lds = (float*)(smem + OFF_G);      // [7][16][68]
  float* xc_lds = (float*)(smem + OFF_XC);    // [(k*64+o)*13 + m]
  float* b2_lds = (float*)(smem + OFF_B2);    // [7][64]
  float* iw_lds = (float*)(smem + OFF_IW);    // [64]
  float* x12_lds = (float*)(smem + OFF_X12);  // [12][64]
  u8* idx_all = (u8*)(smem + OFF_IDXA);       // [511*16]
  float* dt_all = (float*)(smem + OFF_DTA);   // [511*16]

  const int tid = threadIdx.x;
  const int bid = blockIdx.x;
  const int grp = bid & 7;
  const int j = bid >> 3;
  const int b0 = grp * MBQ;
  const int wave = tid >> 6;
  const int q = (tid >> 4) & 3;
  const int c = tid & 15;
  const int kloc0 = 2 * j;  // local K tiles (32-wide) are {2j, 2j+1}

  u16* hbuf = (u16*)(ws + WS_HBUF);
  int* bars = (int*)(ws + WS_BAR);
  int* myflag = bars + grp * 128 + j * 32;

  // ---- prologue ----
  for (int p = tid; p < 12 * 64; p += 512) x12_lds[p] = ((const float*)(ws + WS_X12))[p];
  for (int p = tid; p < 16 * 264 / 2; p += 512) ((unsigned*)h_lds)[p] = 0u;  // h(0)=0
  if (tid < 448) {
    int kk = tid >> 6, o = tid & 63;
    b2_lds[kk * 64 + o] = gb2[kk * 256 + j * 64 + o];
  }
  if (tid < 64) iw_lds[tid] = iW[j * 256 + j * 64 + tid];
  const float ibj = ibp[j];
  // preload all per-step indices / dts into LDS
  for (int p = tid; p < STEPS * 16; p += 512) {
    int t = p >> 4, b = p & 15;
    idx_all[p] = (u8)(ev[(b0 + b) * NT + t] * 3 + mk[(b0 + b) * NT + t]);
    dt_all[p] = ts[(b0 + b) * NT + t + 1];
  }
  __syncthreads();
  // xc table: xc[k][o][m] = g_b1[k][j*64+o] + sum_i x12[m][i] * W1[k][j*64+o][i]
  if (tid < 448) {
    int kk = tid >> 6, o = tid & 63;
    const float* row = gW1 + (size_t)(kk * 256 + j * 64 + o) * 320;
    float a[12];
    float bb = gb1[kk * 256 + j * 64 + o];
    #pragma unroll
    for (int m = 0; m < 12; ++m) a[m] = bb;
    for (int i = 0; i < 64; ++i) {
      float w = row[i];
      #pragma unroll
      for (int m = 0; m < 12; ++m) a[m] += x12_lds[m * 64 + i] * w;
    }
    #pragma unroll
    for (int m = 0; m < 12; ++m) xc_lds[(kk * 64 + o) * 13 + m] = a[m];
  }

  // weight fragments (register-resident bf16, 160 regs/wave).
  // Slot order: s=0..5 remote K tiles (kt = s + (s >= 2j ? 2 : 0)), s=6..7 local tiles.
  s16x8 a1[4][8];  // W1 h-part: M=64 (o), K=256 (h)
  s16x8 a2[4][2];  // W2 block:  M=64 (o), K=64 (g)
  const int k = wave;
  if (wave < 7) {
    #pragma unroll
    for (int s = 0; s < 8; ++s) {
      int kt = (s < 6) ? (s + (s >= kloc0 ? 2 : 0)) : (kloc0 + (s - 6));
      #pragma unroll
      for (int mt = 0; mt < 4; ++mt) {
        const float* p = gW1 + (size_t)(k * 256 + j * 64 + 16 * mt + c) * 320 + 64 + 32 * kt + 8 * q;
        union { s16x8 v; u16 u[8]; } fr;
        #pragma unroll
        for (int i = 0; i < 8; ++i) fr.u[i] = f2bf(p[i]);
        a1[mt][s] = fr.v;
      }
    }
    #pragma unroll
    for (int mt = 0; mt < 4; ++mt)
      #pragma unroll
      for (int kt = 0; kt < 2; ++kt) {
        const float* p = gW2 + (size_t)(k * 256 + j * 64 + 16 * mt + c) * 256 + j * 64 + 32 * kt + 8 * q;
        union { s16x8 v; u16 u[8]; } fr;
        #pragma unroll
        for (int i = 0; i < 8; ++i) fr.u[i] = f2bf(p[i]);
        a2[mt][kt] = fr.v;
      }
  }

  float ccA[2] = {0.f, 0.f};   // c state
  float cctA[2] = {0.f, 0.f};  // c_target state
  f32x4 acc[4] = {};           // GEMM1 accumulator (local tiles pre-accumulated at bottom)
  const f32x4 fzero = {};
  __syncthreads();

  const int O_CELL = NB * STEPS * 4;
  const int SZB = NB * STEPS * NH;
  const int O_CT = O_CELL + SZB;
  const int O_OUT = O_CT + SZB;
  const int O_DEC = O_OUT + SZB;

  for (int t = 0; t < STEPS; ++t) {
    // ---- top: GEMM1 remote tiles, tanh, GEMM2 ----
    if (wave < 7) {
      #pragma unroll
      for (int s = 0; s < 6; ++s) {
        int ks = s + (s >= kloc0 ? 2 : 0);
        s16x8 bf = *(const s16x8*)&h_lds[c * 264 + 32 * ks + 8 * q];
        #pragma unroll
        for (int mt = 0; mt < 4; ++mt)
          acc[mt] = __builtin_amdgcn_mfma_f32_16x16x32_bf16(a1[mt][s], bf, acc[mt], 0, 0, 0);
      }
      u16* preW = (u16*)(smem + OFF_PRE) + k * (16 * 72);
      int midx = (int)idx_all[t * 16 + c];
      #pragma unroll
      for (int mt = 0; mt < 4; ++mt) {
        int o = 16 * mt + 4 * q;
        const float* xr = &xc_lds[(k * 64 + o) * 13 + midx];
        u16 u0 = f2bf(tanh_fast(acc[mt][0] + xr[0]));
        u16 u1 = f2bf(tanh_fast(acc[mt][1] + xr[13]));
        u16 u2 = f2bf(tanh_fast(acc[mt][2] + xr[26]));
        u16 u3 = f2bf(tanh_fast(acc[mt][3] + xr[39]));
        u32x2 pk;
        pk[0] = (unsigned)u0 | ((unsigned)u1 << 16);
        pk[1] = (unsigned)u2 | ((unsigned)u3 << 16);
        *(u32x2*)&preW[c * 72 + o] = pk;  // pre[b=c][o..o+3], bf16
      }
      f32x4 acc2[4] = {};
      #pragma unroll
      for (int kt = 0; kt < 2; ++kt) {
        s16x8 pf = *(const s16x8*)&preW[c * 72 + 32 * kt + 8 * q];
        #pragma unroll
        for (int mt = 0; mt < 4; ++mt)
          acc2[mt] = __builtin_amdgcn_mfma_f32_16x16x32_bf16(a2[mt][kt], pf, acc2[mt], 0, 0, 0);
      }
      #pragma unroll
      for (int mt = 0; mt < 4; ++mt)
        *(f32x4*)&g_lds[(k * 16 + c) * 68 + 16 * mt + 4 * q] = acc2[mt];
    }
    __syncthreads();

    // ---- phase C: gates, cell update, h_new ----
    const int b = tid >> 5, o2 = (tid & 31) * 2;
    float ip = 0.f;
    float ci[2], ctn[2], opv[2], dcv[2];
    {
      float dtv = dt_all[t * 16 + b];
      float G[7][2];
      #pragma unroll
      for (int kk = 0; kk < 7; ++kk) {
        f32x2 gg = *(const f32x2*)&g_lds[(kk * 16 + b) * 68 + o2];
        G[kk][0] = gg[0] + b2_lds[kk * 64 + o2];
        G[kk][1] = gg[1] + b2_lds[kk * 64 + o2 + 1];
      }
      float hnv[2];
      #pragma unroll
      for (int e = 0; e < 2; ++e) {
        float inp = sigm(G[0][e]);
        float fg = sigm(G[1][e]);
        float op = sigm(G[2][e]);
        float itg = sigm(G[3][e]);
        float ftg = sigm(G[4][e]);
        float z = tanh_fast(G[5][e]);
        float dc = softplus_f(G[6][e]);
        float c_i = fg * ccA[e] + inp * z;
        float c_t = ftg * cctA[e] + itg * z;
        float edv = __expf(-dc * dtv);
        float c_n = c_t + (c_i - c_t) * edv;
        float h_n = op * tanh_fast(c_n);
        ccA[e] = c_n;
        cctA[e] = c_t;
        ci[e] = c_i; ctn[e] = c_t; opv[e] = op; dcv[e] = dc;
        hnv[e] = h_n;
        ip += iw_lds[o2 + e] * h_n;
      }
      unsigned hp = (unsigned)f2bf(hnv[0]) | ((unsigned)f2bf(hnv[1]) << 16);
      if (t < STEPS - 1) {
        *(unsigned*)&h_lds[b * 264 + j * 64 + o2] = hp;  // local columns of h(t+1)
        __hip_atomic_store((unsigned*)&hbuf[((size_t)(((t + 1) & 1) * GQ + grp) * MBQ + b) * 256 + j * 64 + o2],
                           hp, __ATOMIC_RELAXED, __HIP_MEMORY_SCOPE_AGENT);
      }
    }
    __syncthreads();  // drains h stores (vmcnt 0) + orders h_lds local writes

    // ---- arrive: publish own flag ----
    if (tid == 0 && t < STEPS - 1)
      __hip_atomic_store(myflag, t + 1, __ATOMIC_RELAXED, __HIP_MEMORY_SCOPE_AGENT);

    // C2: output stores + intensity (L2-backed normal stores)
    auto C2 = [&]() {
      size_t base = ((size_t)(b0 + b) * STEPS + t) * NH + j * 64 + o2;
      f32x2 v;
      v[0] = ci[0];  v[1] = ci[1];  *(f32x2*)&out[O_CELL + base] = v;
      v[0] = ctn[0]; v[1] = ctn[1]; *(f32x2*)&out[O_CT + base] = v;
      v[0] = opv[0]; v[1] = opv[1]; *(f32x2*)&out[O_OUT + base] = v;
      v[0] = dcv[0]; v[1] = dcv[1]; *(f32x2*)&out[O_DEC + base] = v;
      #pragma unroll
      for (int d = 1; d < 32; d <<= 1) ip += __shfl_xor(ip, d, 32);
      if ((tid & 31) == 0)
        out[((size_t)(b0 + b) * STEPS + t) * 4 + j] = softplus_f(ip + ibj);
    };

    if (t < STEPS - 1) {
      if (wave < 7) {
        // GEMM1 local tiles of h(t+1) while wave 7 fetches remote h
        #pragma unroll
        for (int mt = 0; mt < 4; ++mt) acc[mt] = fzero;
        #pragma unroll
        for (int s = 6; s < 8; ++s) {
          int ks = kloc0 + (s - 6);
          s16x8 bf = *(const s16x8*)&h_lds[c * 264 + 32 * ks + 8 * q];
          #pragma unroll
          for (int mt = 0; mt < 4; ++mt)
            acc[mt] = __builtin_amdgcn_mfma_f32_16x16x32_bf16(a1[mt][s], bf, acc[mt], 0, 0, 0);
        }
        C2();
      } else {
        C2();
        // wave 7: poll remote flags, pull 3x2KB of remote h(t+1)
        const int l = tid & 63;
        const int row = l >> 2;
        const int segb = (l & 3) * 32;  // byte offset within the 128B row-chunk
        int* f0p = bars + grp * 128 + (0 + (0 >= j)) * 32;
        int* f1p = bars + grp * 128 + (1 + (1 >= j)) * 32;
        int* f2p = bars + grp * 128 + (2 + (2 >= j)) * 32;
        for (;;) {
          int f0 = __hip_atomic_load(f0p, __ATOMIC_RELAXED, __HIP_MEMORY_SCOPE_AGENT);
          int f1 = __hip_atomic_load(f1p, __ATOMIC_RELAXED, __HIP_MEMORY_SCOPE_AGENT);
          int f2 = __hip_atomic_load(f2p, __ATOMIC_RELAXED, __HIP_MEMORY_SCOPE_AGENT);
          if (f0 > t && f1 > t && f2 > t) break;
          __builtin_amdgcn_s_sleep(1);
        }
        const char* rbase = (const char*)hbuf +
            ((size_t)(((t + 1) & 1) * GQ + grp) * MBQ + row) * 512 + segb;
        u64 dv[3][4];
        #pragma unroll
        for (int rb = 0; rb < 3; ++rb) {
          int jr = rb + (rb >= j);
          const u64* src = (const u64*)(rbase + jr * 128);
          #pragma unroll
          for (int kq = 0; kq < 4; ++kq)
            dv[rb][kq] = __hip_atomic_load(src + kq, __ATOMIC_RELAXED, __HIP_MEMORY_SCOPE_AGENT);
        }
        char* lbase = (char*)h_lds + row * 528 + segb;
        #pragma unroll
        for (int rb = 0; rb < 3; ++rb) {
          int jr = rb + (rb >= j);
          #pragma unroll
          for (int kq = 0; kq < 4; ++kq)
            *(u64*)(lbase + jr * 128 + 8 * kq) = dv[rb][kq];
        }
      }
      __syncthreads();  // remote h_lds writes visible to all waves
    } else {
      C2();
    }
  }
}

extern "C" void kernel_launch(void* const* d_in, const int* in_sizes, int n_in,
                              void* d_out, int out_size, void* d_ws, size_t ws_size,
                              hipStream_t stream) {
  const int* ev = (const int*)d_in[0];
  const float* ts = (const float*)d_in[1];
  const int* mk = (const int*)d_in[2];
  const float* etW1 = (const float*)d_in[3];
  const float* etb1 = (const float*)d_in[4];
  const float* etW2 = (const float*)d_in[5];
  const float* etb2 = (const float*)d_in[6];
  const float* esW1 = (const float*)d_in[7];
  const float* esb1 = (const float*)d_in[8];
  const float* esW2 = (const float*)d_in[9];
  const float* esb2 = (const float*)d_in[10];
  const float* gW1 = (const float*)d_in[11];
  const float* gb1 = (const float*)d_in[12];
  const float* gW2 = (const float*)d_in[13];
  const float* gb2 = (const float*)d_in[14];
  const float* iW = (const float*)d_in[15];
  const float* ibv = (const float*)d_in[16];
  char* ws = (char*)d_ws;
  float* out = (float*)d_out;

  ct4_prep<<<1, 64, 0, stream>>>(etW1, etb1, etW2, etb2, esW1, esb1, esW2, esb2, ws);
  (void)hipFuncSetAttribute((const void*)ct4_main,
                            hipFuncAttributeMaxDynamicSharedMemorySize, SMEM_BYTES);
  ct4_main<<<GQ * 4, 512, SMEM_BYTES, stream>>>(ev, ts, mk, gW1, gb1, gW2, gb2, iW, ibv, out, ws);
}